// Round 1
// baseline (734.140 us; speedup 1.0000x reference)
//
#include <hip/hip_runtime.h>

#define VV 1000
#define OO 64
#define LL 64
#define BB 128

// spart layout (floats): per branch region, [o][chunk][f][b], b innermost
// region bases (floats): br0=0, br1=163840, br2=819200, br3=2293760; total 4915200

// ---------------------------------------------------------------------------
// Kernel 1: per-(v,l) 128-bit batch masks. mask[v*64+l] = {bits b0..63, bits b64..127}
__global__ void build_masks(const int* __restrict__ tokens,
                            unsigned long long* __restrict__ mask) {
    int i = blockIdx.x * 256 + threadIdx.x;   // 0..8191 == b*64 + l
    int b = i >> 6, l = i & 63;
    int v = tokens[i];
    atomicOr(&mask[(((long)v << 6) | l) * 2 + (b >> 6)], 1ull << (b & 63));
}

// ---------------------------------------------------------------------------
// Templated per-branch worker: U v-values in flight per wave iteration.
// 256 threads = 4 waves per block.
template<int FH, int U, int NCH>
__device__ __forceinline__ void run_branch(
    const float* __restrict__ W,
    const ulonglong2* __restrict__ mask,
    float* __restrict__ spart, long base,
    int o, int ch, int vc, float* s)
{
    int tid  = threadIdx.x;
    int lane = tid & 63;
    int wv   = tid >> 6;          // 4 waves/block

    int v0 = ch * vc;
    int v1 = min(VV, v0 + vc);

    for (int i = tid; i < FH * 128; i += 256) s[i] = 0.f;
    __syncthreads();

    const float* slab = W + (long)o * (VV * FH * LL);   // W[o, v, f, l]

    // wave wv owns v = v0+wv, v0+wv+4, ... ; grouped U at a time
    for (int vg = v0 + wv; vg < v1; vg += 4 * U) {
        ulonglong2 m[U];
        bool act[U];
        int vu[U];
        #pragma unroll
        for (int u = 0; u < U; ++u) {
            vu[u] = vg + 4 * u;
            if (vu[u] < v1) {
                m[u] = mask[(vu[u] << 6) | lane];
            } else {
                m[u].x = 0; m[u].y = 0;
            }
            act[u] = (m[u].x | m[u].y) != 0ull;
        }

        float w[U][FH];
        #pragma unroll
        for (int u = 0; u < U; ++u) {
            if (act[u]) {
                const float* row = slab + (long)vu[u] * (FH * LL) + lane;
                #pragma unroll
                for (int f = 0; f < FH; ++f)
                    w[u][f] = __builtin_nontemporal_load(row + f * LL);
            }
        }

        #pragma unroll
        for (int u = 0; u < U; ++u) {
            if (act[u]) {
                unsigned long long mm = m[u].x;
                while (mm) {
                    int b = __ffsll(mm) - 1; mm &= mm - 1;
                    float* sp = s + b;
                    #pragma unroll
                    for (int f = 0; f < FH; ++f) atomicAdd(&sp[f * 128], w[u][f]);
                }
                mm = m[u].y;
                while (mm) {
                    int b = __ffsll(mm) - 1; mm &= mm - 1;
                    float* sp = s + 64 + b;
                    #pragma unroll
                    for (int f = 0; f < FH; ++f) atomicAdd(&sp[f * 128], w[u][f]);
                }
            }
        }
    }
    __syncthreads();

    float* out = spart + base + ((long)(o * NCH + ch) * FH) * 128;
    for (int i = tid; i < FH * 128; i += 256) out[i] = s[i];
}

// ---------------------------------------------------------------------------
__global__ __launch_bounds__(256) void branch_accum(
    const float* __restrict__ W0, const float* __restrict__ W1,
    const float* __restrict__ W2, const float* __restrict__ W3,
    const ulonglong2* __restrict__ mask,
    float* __restrict__ spart)
{
    __shared__ float s[20 * 128];   // 10 KB (max FH)

    int id = blockIdx.x;
    if (id < 256) {
        int t = id;        run_branch<5, 6, 4>  (W0, mask, spart, 0,       t >> 2, t & 3,  250, s);
    } else if (id < 768) {
        int t = id - 256;  run_branch<10, 3, 8> (W1, mask, spart, 163840,  t >> 3, t & 7,  125, s);
    } else if (id < 1536) {
        int t = id - 768;  run_branch<15, 2, 12>(W2, mask, spart, 819200,  t / 12, t % 12, 84,  s);
    } else {
        int t = id - 1536; run_branch<20, 1, 16>(W3, mask, spart, 2293760, t >> 4, t & 15, 63,  s);
    }
}

// ---------------------------------------------------------------------------
template<int FH, int NCH>
__device__ __forceinline__ void reduce_branch(
    const float* __restrict__ p, float bo, float* __restrict__ feats,
    int blk, int b)
{
    float mmax = 0.f;     // relu folds into max with 0
    #pragma unroll
    for (int f = 0; f < FH; ++f) {
        float tot = 0.f;
        #pragma unroll
        for (int ch = 0; ch < NCH; ++ch) tot += p[(ch * FH + f) * 128 + b];
        mmax = fmaxf(mmax, tot + bo);
    }
    feats[blk * 128 + b] = mmax * rsqrtf(1.f + mmax * mmax);
}

__global__ void reduce_act(const float* __restrict__ spart,
                           const float* __restrict__ b0, const float* __restrict__ b1,
                           const float* __restrict__ b2, const float* __restrict__ b3,
                           float* __restrict__ feats)
{
    int blk = blockIdx.x;        // 0..255 = br*64 + o
    int br = blk >> 6, o = blk & 63;
    int b = threadIdx.x;         // 0..127

    if (br == 0)
        reduce_branch<5, 4>  (spart + (long)(o * 4) * 5 * 128,             b0[o], feats, blk, b);
    else if (br == 1)
        reduce_branch<10, 8> (spart + 163840 + (long)(o * 8) * 10 * 128,   b1[o], feats, blk, b);
    else if (br == 2)
        reduce_branch<15, 12>(spart + 819200 + (long)(o * 12) * 15 * 128,  b2[o], feats, blk, b);
    else
        reduce_branch<20, 16>(spart + 2293760 + (long)(o * 16) * 20 * 128, b3[o], feats, blk, b);
}

// ---------------------------------------------------------------------------
__global__ void final_linear(const float* __restrict__ feats,
                             const float* __restrict__ Wlin,
                             const float* __restrict__ blin,
                             float* __restrict__ out)
{
    int t = threadIdx.x;         // 256 threads: b = t>>1, j = t&1
    int b = t >> 1, j = t & 1;
    float acc = blin[j];
    #pragma unroll 8
    for (int k = 0; k < 256; ++k)
        acc += feats[k * 128 + b] * Wlin[j * 256 + k];
    out[b * 2 + j] = acc;
}

// ---------------------------------------------------------------------------
extern "C" void kernel_launch(void* const* d_in, const int* in_sizes, int n_in,
                              void* d_out, int out_size, void* d_ws, size_t ws_size,
                              hipStream_t stream) {
    const int*   tokens = (const int*)  d_in[0];
    const float* W1     = (const float*)d_in[1];
    const float* b1     = (const float*)d_in[2];
    const float* W2     = (const float*)d_in[3];
    const float* b2     = (const float*)d_in[4];
    const float* W3     = (const float*)d_in[5];
    const float* b3     = (const float*)d_in[6];
    const float* W4     = (const float*)d_in[7];
    const float* b4     = (const float*)d_in[8];
    const float* Wlin   = (const float*)d_in[9];
    const float* blin   = (const float*)d_in[10];
    float* out = (float*)d_out;

    char* ws = (char*)d_ws;
    unsigned long long* mask = (unsigned long long*)ws;        // 1,024,000 B
    float* spart = (float*)(ws + 1048576);                     // 19,660,800 B
    float* feats = (float*)(ws + 1048576 + 19660800);          // 131,072 B

    hipMemsetAsync(mask, 0, 64000 * 2 * sizeof(unsigned long long), stream);
    build_masks<<<32, 256, 0, stream>>>(tokens, mask);
    branch_accum<<<2560, 256, 0, stream>>>(W1, W2, W3, W4,
                                           (const ulonglong2*)mask, spart);
    reduce_act<<<256, 128, 0, stream>>>(spart, b1, b2, b3, b4, feats);
    final_linear<<<1, 256, 0, stream>>>(feats, Wlin, blin, out);
}

// Round 2
// 713.458 us; speedup vs baseline: 1.0290x; 1.0290x over previous
//
#include <hip/hip_runtime.h>

#define VV 1000
#define OO 64
#define LL 64
#define BB 128

// spart layout (floats): per branch region, [o][chunk][f][b], b innermost
// region bases (floats): br0=0, br1=81920, br2=409600, br3=1146880; total 2457600

// ---------------------------------------------------------------------------
// Kernel 1: per-(v,l) 128-bit batch masks. mask[v*64+l] = {bits b0..63, bits b64..127}
__global__ void build_masks(const int* __restrict__ tokens,
                            unsigned long long* __restrict__ mask) {
    int i = blockIdx.x * 256 + threadIdx.x;   // 0..8191 == b*64 + l
    int b = i >> 6, l = i & 63;
    int v = tokens[i];
    atomicOr(&mask[(((long)v << 6) | l) * 2 + (b >> 6)], 1ull << (b & 63));
}

// ---------------------------------------------------------------------------
// Templated per-branch worker: U v-values in flight per wave iteration.
template<int FH, int U, int NCH>
__device__ __forceinline__ void run_branch(
    const float* __restrict__ W,
    const ulonglong2* __restrict__ mask,
    float* __restrict__ spart, long base,
    int o, int ch, int vc, float* s)
{
    int tid  = threadIdx.x;
    int lane = tid & 63;
    int wv   = tid >> 6;          // 8 waves/block

    int v0 = ch * vc;
    int v1 = min(VV, v0 + vc);

    for (int i = tid; i < FH * 128; i += 512) s[i] = 0.f;
    __syncthreads();

    const float* slab = W + (long)o * (VV * FH * LL);   // W[o, v, f, l]

    // wave wv owns v = v0+wv, v0+wv+8, ... ; grouped U at a time
    for (int vg = v0 + wv; vg < v1; vg += 8 * U) {
        ulonglong2 m[U];
        bool act[U];
        int vu[U];
        #pragma unroll
        for (int u = 0; u < U; ++u) {
            vu[u] = vg + 8 * u;
            if (vu[u] < v1) {
                m[u] = mask[(vu[u] << 6) | lane];
            } else {
                m[u].x = 0; m[u].y = 0;
            }
            act[u] = (m[u].x | m[u].y) != 0ull;
        }

        float w[U][FH];
        #pragma unroll
        for (int u = 0; u < U; ++u) {
            if (act[u]) {
                const float* row = slab + (long)vu[u] * (FH * LL) + lane;
                #pragma unroll
                for (int f = 0; f < FH; ++f)
                    w[u][f] = __builtin_nontemporal_load(row + f * LL);
            }
        }

        #pragma unroll
        for (int u = 0; u < U; ++u) {
            if (act[u]) {
                unsigned long long mm = m[u].x;
                while (mm) {
                    int b = __ffsll(mm) - 1; mm &= mm - 1;
                    float* sp = s + b;
                    #pragma unroll
                    for (int f = 0; f < FH; ++f) atomicAdd(&sp[f * 128], w[u][f]);
                }
                mm = m[u].y;
                while (mm) {
                    int b = __ffsll(mm) - 1; mm &= mm - 1;
                    float* sp = s + 64 + b;
                    #pragma unroll
                    for (int f = 0; f < FH; ++f) atomicAdd(&sp[f * 128], w[u][f]);
                }
            }
        }
    }
    __syncthreads();

    float* out = spart + base + ((long)(o * NCH + ch) * FH) * 128;
    for (int i = tid; i < FH * 128; i += 512) out[i] = s[i];
}

// ---------------------------------------------------------------------------
__global__ __launch_bounds__(512) void branch_accum(
    const float* __restrict__ W0, const float* __restrict__ W1,
    const float* __restrict__ W2, const float* __restrict__ W3,
    const ulonglong2* __restrict__ mask,
    float* __restrict__ spart)
{
    __shared__ float s[20 * 128];   // 10 KB (max FH)

    int id = blockIdx.x;
    if (id < 128) {
        int t = id;       run_branch<5, 6, 2>(W0, mask, spart, 0,       t >> 1, t & 1, 500, s);
    } else if (id < 384) {
        int t = id - 128; run_branch<10, 3, 4>(W1, mask, spart, 81920,  t >> 2, t & 3, 250, s);
    } else if (id < 768) {
        int t = id - 384; run_branch<15, 2, 6>(W2, mask, spart, 409600, t / 6,  t % 6, 167, s);
    } else {
        int t = id - 768; run_branch<20, 1, 8>(W3, mask, spart, 1146880, t >> 3, t & 7, 125, s);
    }
}

// ---------------------------------------------------------------------------
template<int FH, int NCH>
__device__ __forceinline__ void reduce_branch(
    const float* __restrict__ p, float bo, float* __restrict__ feats,
    int blk, int b)
{
    float mmax = 0.f;     // relu folds into max with 0
    #pragma unroll
    for (int f = 0; f < FH; ++f) {
        float tot = 0.f;
        #pragma unroll
        for (int ch = 0; ch < NCH; ++ch) tot += p[(ch * FH + f) * 128 + b];
        mmax = fmaxf(mmax, tot + bo);
    }
    feats[blk * 128 + b] = mmax * rsqrtf(1.f + mmax * mmax);
}

__global__ void reduce_act(const float* __restrict__ spart,
                           const float* __restrict__ b0, const float* __restrict__ b1,
                           const float* __restrict__ b2, const float* __restrict__ b3,
                           float* __restrict__ feats)
{
    int blk = blockIdx.x;        // 0..255 = br*64 + o
    int br = blk >> 6, o = blk & 63;
    int b = threadIdx.x;         // 0..127

    if (br == 0)
        reduce_branch<5, 2>(spart + (long)(o * 2) * 5 * 128,            b0[o], feats, blk, b);
    else if (br == 1)
        reduce_branch<10, 4>(spart + 81920 + (long)(o * 4) * 10 * 128,  b1[o], feats, blk, b);
    else if (br == 2)
        reduce_branch<15, 6>(spart + 409600 + (long)(o * 6) * 15 * 128, b2[o], feats, blk, b);
    else
        reduce_branch<20, 8>(spart + 1146880 + (long)(o * 8) * 20 * 128, b3[o], feats, blk, b);
}

// ---------------------------------------------------------------------------
__global__ void final_linear(const float* __restrict__ feats,
                             const float* __restrict__ Wlin,
                             const float* __restrict__ blin,
                             float* __restrict__ out)
{
    int t = threadIdx.x;         // 256 threads: b = t>>1, j = t&1
    int b = t >> 1, j = t & 1;
    float acc = blin[j];
    #pragma unroll 8
    for (int k = 0; k < 256; ++k)
        acc += feats[k * 128 + b] * Wlin[j * 256 + k];
    out[b * 2 + j] = acc;
}

// ---------------------------------------------------------------------------
extern "C" void kernel_launch(void* const* d_in, const int* in_sizes, int n_in,
                              void* d_out, int out_size, void* d_ws, size_t ws_size,
                              hipStream_t stream) {
    const int*   tokens = (const int*)  d_in[0];
    const float* W1     = (const float*)d_in[1];
    const float* b1     = (const float*)d_in[2];
    const float* W2     = (const float*)d_in[3];
    const float* b2     = (const float*)d_in[4];
    const float* W3     = (const float*)d_in[5];
    const float* b3     = (const float*)d_in[6];
    const float* W4     = (const float*)d_in[7];
    const float* b4     = (const float*)d_in[8];
    const float* Wlin   = (const float*)d_in[9];
    const float* blin   = (const float*)d_in[10];
    float* out = (float*)d_out;

    char* ws = (char*)d_ws;
    unsigned long long* mask = (unsigned long long*)ws;        // 1,024,000 B
    float* spart = (float*)(ws + 1048576);                     // 9,830,400 B
    float* feats = (float*)(ws + 1048576 + 9830400);           // 131,072 B

    hipMemsetAsync(mask, 0, 64000 * 2 * sizeof(unsigned long long), stream);
    build_masks<<<32, 256, 0, stream>>>(tokens, mask);
    branch_accum<<<1280, 512, 0, stream>>>(W1, W2, W3, W4,
                                           (const ulonglong2*)mask, spart);
    reduce_act<<<256, 128, 0, stream>>>(spart, b1, b2, b3, b4, feats);
    final_linear<<<1, 256, 0, stream>>>(feats, Wlin, blin, out);
}